// Round 6
// baseline (325.336 us; speedup 1.0000x reference)
//
#include <hip/hip_runtime.h>
#include <hip/hip_bf16.h>
#include <stdint.h>

#define B_   2
#define N_   2048
#define DIN  2048
#define DOUT 2048
#define H_   32
#define G_   8
#define HD_  64
#define M_   (B_*N_)   // 4096

using short8 = __attribute__((ext_vector_type(8))) short;
using f32x4  = __attribute__((ext_vector_type(4))) float;
using f32x16 = __attribute__((ext_vector_type(16))) float;
using int4v  = __attribute__((ext_vector_type(4))) int;

__device__ __forceinline__ unsigned short f2bf(float f) {
  unsigned int u = __float_as_uint(f);
  unsigned int r = u + 0x7FFFu + ((u >> 16) & 1u);
  return (unsigned short)(r >> 16);
}
__device__ __forceinline__ float bf2f(unsigned short h) {
  return __uint_as_float(((unsigned int)h) << 16);
}

// ---------------- elementwise f32 -> bf16 (4 elems/thread) ----------------
__global__ void k_cvt(const float* __restrict__ in, unsigned short* __restrict__ out, int n4) {
  int i = blockIdx.x * 256 + threadIdx.x;
  if (i >= n4) return;
  float4 v = reinterpret_cast<const float4*>(in)[i];
  uint2 o;
  o.x = (unsigned int)f2bf(v.x) | ((unsigned int)f2bf(v.y) << 16);
  o.y = (unsigned int)f2bf(v.z) | ((unsigned int)f2bf(v.w) << 16);
  reinterpret_cast<uint2*>(out)[i] = o;
}

// ---------------- transpose + convert: W (R x C) f32 -> Wt (C x R) bf16 ----------------
__global__ void k_transpose(const float* __restrict__ W, unsigned short* __restrict__ Wt,
                            int R, int C) {
  __shared__ float tile[32][33];
  int c0 = blockIdx.x * 32, r0 = blockIdx.y * 32;
  int tx = threadIdx.x, ty = threadIdx.y;  // (32,8)
  #pragma unroll
  for (int j = 0; j < 4; ++j)
    tile[ty + j*8][tx] = W[(size_t)(r0 + ty + j*8) * C + c0 + tx];
  __syncthreads();
  #pragma unroll
  for (int j = 0; j < 4; ++j)
    Wt[(size_t)(c0 + ty + j*8) * R + r0 + tx] = f2bf(tile[tx][ty + j*8]);
}

// ---------------- bf16 V-transpose: KVb V-half -> Vt[(b*8+g)*64 + d][n] ----------------
__global__ void k_vtrans(const unsigned short* __restrict__ KV, unsigned short* __restrict__ Vt) {
  __shared__ unsigned short tile[32][33];
  int nt = blockIdx.x;   // 0..63 (n tile)
  int dt = blockIdx.y;   // 0..1  (d tile)
  int bg = blockIdx.z;   // 0..15 (b*8+g)
  int b = bg >> 3, g = bg & 7;
  int tx = threadIdx.x, ty = threadIdx.y;  // (32,8)
  const unsigned short* src = KV + (size_t)(b*2048 + nt*32) * 1024 + 512 + g*64 + dt*32;
  #pragma unroll
  for (int j = 0; j < 4; ++j)
    tile[ty + j*8][tx] = src[(size_t)(ty + j*8) * 1024 + tx];   // [n_local][d_local]
  __syncthreads();
  unsigned short* dst = Vt + ((size_t)bg*64 + dt*32) * (size_t)N_ + nt*32;
  #pragma unroll
  for (int j = 0; j < 4; ++j)
    dst[(size_t)(ty + j*8) * N_ + tx] = tile[tx][ty + j*8];     // [d_local][n_local]
}

// ---------------- fragment-linear K/V tile pack ----------------
// Kp/Vp: per (bg, t) a 2048-element (4 KB) tile laid out EXACTLY in load order:
//   element index = chunk*512 + lane*8 + j.
__global__ void __launch_bounds__(64)
k_pack(const unsigned short* __restrict__ KV, const unsigned short* __restrict__ Vt,
       unsigned short* __restrict__ Kp, unsigned short* __restrict__ Vp) {
  const int t  = blockIdx.x;      // 0..63
  const int bg = blockIdx.y;      // 0..15
  const int b = bg >> 3, g = bg & 7;
  const int l = threadIdx.x;
  const int lo = l & 31, hi = l >> 5;
  const size_t base = ((size_t)bg*64 + t) * 2048;
  #pragma unroll
  for (int c = 0; c < 4; ++c) {
    short8 kv = *reinterpret_cast<const short8*>(
        KV + (size_t)(b*2048 + t*32 + lo) * 1024 + g*64 + c*16 + hi*8);
    *reinterpret_cast<short8*>(Kp + base + c*512 + l*8) = kv;
    short8 vv = *reinterpret_cast<const short8*>(
        Vt + ((size_t)bg*64 + (c>>1)*32 + lo) * (size_t)N_ + t*32 + (c&1)*16 + hi*8);
    *reinterpret_cast<short8*>(Vp + base + c*512 + l*8) = vv;
  }
}

// ---------------- in-place RoPE on bf16, optional output scale ----------------
__global__ void k_rope(unsigned short* __restrict__ X, const float* __restrict__ cosT,
                       const float* __restrict__ sinT, int nheads, int rowStride, float scale) {
  int idx = blockIdx.x * 256 + threadIdx.x;
  int dp  = idx & 31;
  int hh  = (idx >> 5) % nheads;
  int row = idx / (32 * nheads);
  if (row >= M_) return;
  int n = row & (N_ - 1);
  float c = cosT[n*HD_ + dp] * scale, s = sinT[n*HD_ + dp] * scale;
  unsigned short* p = X + (size_t)row * rowStride + hh*HD_ + dp;
  float x1 = bf2f(p[0]), x2 = bf2f(p[32]);
  p[0]  = f2bf(x1*c - x2*s);
  p[32] = f2bf(x2*c + x1*s);
}

// ---------------- bf16 GEMM, B given transposed (Bt: N x K row-major) ----------------
// T1: bijective XCD swizzle (m204) so each XCD's L2 serves a contiguous tile strip.
template <typename OUT>
__global__ void __launch_bounds__(256)
k_gemm_bt(const unsigned short* __restrict__ A, const unsigned short* __restrict__ Bt,
          OUT* __restrict__ C, int M, int N, int K) {
  __shared__ unsigned short As[128 * 32];
  __shared__ unsigned short Bs[128 * 32];
  const int tid  = threadIdx.x;
  const int wid  = tid >> 6, l = tid & 63;
  const int lrow = l & 15,  lk = l >> 4;
  const int wm = wid >> 1,  wn = wid & 1;

  // XCD-aware remap: hardware sends block n to XCD n%8; give each XCD a
  // contiguous range of tile ids.
  const int gx   = gridDim.x;
  const int nwg  = gx * gridDim.y;
  const int orig = blockIdx.y * gx + blockIdx.x;
  const int q8   = nwg >> 3, r8 = nwg & 7;
  const int xcd  = orig & 7, lin = orig >> 3;
  const int wg   = (xcd < r8 ? xcd*(q8+1) : r8*(q8+1) + (xcd - r8)*q8) + lin;
  const int bx   = wg % gx, by = wg / gx;

  const int rowA0 = by * 128, rowB0 = bx * 128;

  f32x4 acc[4][4];
  #pragma unroll
  for (int m = 0; m < 4; ++m)
    #pragma unroll
    for (int n = 0; n < 4; ++n)
      #pragma unroll
      for (int r = 0; r < 4; ++r) acc[m][n][r] = 0.f;

  int srow[2], scol[2];
  #pragma unroll
  for (int issue = 0; issue < 2; ++issue) {
    int slot = issue*4096 + wid*1024 + l*16;
    int row  = slot >> 6;
    int cp   = (slot >> 4) & 3;
    int sw   = (row & 3) ^ ((row >> 2) & 3);
    srow[issue] = row;
    scol[issue] = (cp ^ sw) * 8;
  }
  const int swr    = (lrow & 3) ^ ((lrow >> 2) & 3);
  const int rchunk = (lk ^ swr) * 8;

  for (int kt = 0; kt < K; kt += 32) {
    __syncthreads();
    #pragma unroll
    for (int issue = 0; issue < 2; ++issue) {
      const unsigned short* ga = A  + (size_t)(rowA0 + srow[issue]) * K + kt + scol[issue];
      const unsigned short* gb = Bt + (size_t)(rowB0 + srow[issue]) * K + kt + scol[issue];
      __builtin_amdgcn_global_load_lds(
          (const __attribute__((address_space(1))) unsigned int*)ga,
          (__attribute__((address_space(3))) unsigned int*)((char*)As + issue*4096 + wid*1024),
          16, 0, 0);
      __builtin_amdgcn_global_load_lds(
          (const __attribute__((address_space(1))) unsigned int*)gb,
          (__attribute__((address_space(3))) unsigned int*)((char*)Bs + issue*4096 + wid*1024),
          16, 0, 0);
    }
    asm volatile("s_waitcnt vmcnt(0)" ::: "memory");
    __syncthreads();

    short8 av[4], bv[4];
    #pragma unroll
    for (int m = 0; m < 4; ++m)
      av[m] = *reinterpret_cast<const short8*>(&As[(wm*64 + m*16 + lrow)*32 + rchunk]);
    #pragma unroll
    for (int n = 0; n < 4; ++n)
      bv[n] = *reinterpret_cast<const short8*>(&Bs[(wn*64 + n*16 + lrow)*32 + rchunk]);
    #pragma unroll
    for (int m = 0; m < 4; ++m)
      #pragma unroll
      for (int n = 0; n < 4; ++n)
        acc[m][n] = __builtin_amdgcn_mfma_f32_16x16x32_bf16(av[m], bv[n], acc[m][n], 0, 0, 0);
  }

  #pragma unroll
  for (int m = 0; m < 4; ++m) {
    int row0 = rowA0 + wm*64 + m*16 + lk*4;
    #pragma unroll
    for (int n = 0; n < 4; ++n) {
      int col = rowB0 + wn*64 + n*16 + lrow;
      #pragma unroll
      for (int r = 0; r < 4; ++r) {
        float v = acc[m][n][r];
        if constexpr (sizeof(OUT) == 2) C[(size_t)(row0 + r) * N + col] = (OUT)f2bf(v);
        else                            C[(size_t)(row0 + r) * N + col] = v;
      }
    }
  }
}

// ---------------- causal GQA flash attention v6 ----------------
// 4-wave blocks: wave w handles head g*4+w of the same (b,g,qt). Waves are fully
// independent (no LDS/barriers) -> 1024 blocks, ~16 waves/CU for latency hiding.
// Fragment-linear Kp/Vp tiles; longest-qt-first; ping-pong register prefetch;
// Q pre-scaled by 0.125*log2e; T13 defer-max; T12 permlane32_swap P-pack.
__global__ void __launch_bounds__(256, 4)
k_attn(const unsigned short* __restrict__ Q, const unsigned short* __restrict__ Kp,
       const unsigned short* __restrict__ Vp, unsigned short* __restrict__ ctx) {
  const int bid = blockIdx.x;            // 0..1023
  const int c   = bid & 15;              // (b,g) chunk -> fixed XCD pair
  const int b   = c >> 3, g = c & 7;
  const int qt  = 63 - (bid >> 4);       // longest first
  const int hh  = threadIdx.x >> 6;      // wave id = head within group
  const int h   = g*4 + hh;
  const int l   = threadIdx.x & 63;
  const int lq  = l & 31, hi = l >> 5;

  const unsigned short* qp = Q + (size_t)(b*N_ + qt*32 + lq) * DOUT + h*HD_ + hi*8;
  short8 qf0 = *reinterpret_cast<const short8*>(qp);
  short8 qf1 = *reinterpret_cast<const short8*>(qp + 16);
  short8 qf2 = *reinterpret_cast<const short8*>(qp + 32);
  short8 qf3 = *reinterpret_cast<const short8*>(qp + 48);

  const unsigned short* kpb = Kp + (size_t)c*64*2048 + l*8;
  const unsigned short* vpb = Vp + (size_t)c*64*2048 + l*8;

  f32x16 acc0, acc1;
  #pragma unroll
  for (int r = 0; r < 16; ++r) { acc0[r] = 0.f; acc1[r] = 0.f; }
  float m_run = -3.0e38f, l_run = 0.f;

  short8 k0a, k0b, k0c, k0d, v0a, v0b, v0c, v0d;   // ping
  short8 k1a, k1b, k1c, k1d, v1a, v1b, v1c, v1d;   // pong

  auto loadKV = [&](int t, short8& ka, short8& kb, short8& kc, short8& kd,
                            short8& va, short8& vb, short8& vc, short8& vd) {
    const unsigned short* kp = kpb + (size_t)t*2048;
    ka = *reinterpret_cast<const short8*>(kp);
    kb = *reinterpret_cast<const short8*>(kp + 512);
    kc = *reinterpret_cast<const short8*>(kp + 1024);
    kd = *reinterpret_cast<const short8*>(kp + 1536);
    const unsigned short* vp = vpb + (size_t)t*2048;
    va = *reinterpret_cast<const short8*>(vp);
    vb = *reinterpret_cast<const short8*>(vp + 512);
    vc = *reinterpret_cast<const short8*>(vp + 1024);
    vd = *reinterpret_cast<const short8*>(vp + 1536);
  };

  auto body = [&](bool diag, short8& ka, short8& kb, short8& kc, short8& kd,
                             short8& va, short8& vb, short8& vc, short8& vd) {
    f32x16 s;
    #pragma unroll
    for (int r = 0; r < 16; ++r) s[r] = 0.f;
    s = __builtin_amdgcn_mfma_f32_32x32x16_bf16(ka, qf0, s, 0, 0, 0);
    s = __builtin_amdgcn_mfma_f32_32x32x16_bf16(kb, qf1, s, 0, 0, 0);
    s = __builtin_amdgcn_mfma_f32_32x32x16_bf16(kc, qf2, s, 0, 0, 0);
    s = __builtin_amdgcn_mfma_f32_32x32x16_bf16(kd, qf3, s, 0, 0, 0);

    if (diag) {
      #pragma unroll
      for (int r = 0; r < 16; ++r) {
        const int ko = (r & 3) + 8*(r >> 2) + 4*hi;
        s[r] = (ko <= lq) ? s[r] : -3.0e38f;
      }
    }
    float t0 = fmaxf(fmaxf(s[0], s[1]), s[2]);
    float t1 = fmaxf(fmaxf(s[3], s[4]), s[5]);
    float t2 = fmaxf(fmaxf(s[6], s[7]), s[8]);
    float t3 = fmaxf(fmaxf(s[9], s[10]), s[11]);
    float t4 = fmaxf(fmaxf(s[12], s[13]), s[14]);
    float mt = fmaxf(fmaxf(fmaxf(t0, t1), fmaxf(t2, t3)), fmaxf(t4, s[15]));
    mt = fmaxf(mt, __shfl_xor(mt, 32));
    if (!__all(mt <= m_run + 8.f)) {          // T13 defer-max
      float nm = fmaxf(m_run, mt);
      float fr = exp2f(m_run - nm);
      m_run = nm;
      l_run *= fr;
      #pragma unroll
      for (int r = 0; r < 16; ++r) { acc0[r] *= fr; acc1[r] *= fr; }
    }
    unsigned int w[8];
    float ps = 0.f;
    #pragma unroll
    for (int i = 0; i < 8; ++i) {
      float p0 = exp2f(s[2*i]   - m_run);
      float p1 = exp2f(s[2*i+1] - m_run);
      ps += p0 + p1;
      asm("v_cvt_pk_bf16_f32 %0, %1, %2" : "=v"(w[i]) : "v"(p0), "v"(p1));
    }
    ps += __shfl_xor(ps, 32);
    l_run += ps;

    // T12: permlane32_swap builds both halves of each P fragment word
    unsigned int x0 = w[0], x1 = w[1], y0 = w[2], y1 = w[3];
    asm("v_permlane32_swap_b32 %0, %1" : "+v"(x0), "+v"(y0));
    asm("v_permlane32_swap_b32 %0, %1" : "+v"(x1), "+v"(y1));
    unsigned int x2 = w[4], x3 = w[5], y2 = w[6], y3 = w[7];
    asm("v_permlane32_swap_b32 %0, %1" : "+v"(x2), "+v"(y2));
    asm("v_permlane32_swap_b32 %0, %1" : "+v"(x3), "+v"(y3));
    int4v p0i, p1i;
    p0i[0] = (int)x0; p0i[1] = (int)x1; p0i[2] = (int)y0; p0i[3] = (int)y1;
    p1i[0] = (int)x2; p1i[1] = (int)x3; p1i[2] = (int)y2; p1i[3] = (int)y3;
    short8 pa0 = __builtin_bit_cast(short8, p0i);
    short8 pa1 = __builtin_bit_cast(short8, p1i);

    acc0 = __builtin_amdgcn_mfma_f32_32x32x16_bf16(va, pa0, acc0, 0, 0, 0);
    acc0 = __builtin_amdgcn_mfma_f32_32x32x16_bf16(vb, pa1, acc0, 0, 0, 0);
    acc1 = __builtin_amdgcn_mfma_f32_32x32x16_bf16(vc, pa0, acc1, 0, 0, 0);
    acc1 = __builtin_amdgcn_mfma_f32_32x32x16_bf16(vd, pa1, acc1, 0, 0, 0);
  };

  loadKV(0, k0a, k0b, k0c, k0d, v0a, v0b, v0c, v0d);
  int t = 0;
  while (true) {
    if (t + 1 <= qt) loadKV(t + 1, k1a, k1b, k1c, k1d, v1a, v1b, v1c, v1d);
    body(t == qt, k0a, k0b, k0c, k0d, v0a, v0b, v0c, v0d);
    if (++t > qt) break;
    if (t + 1 <= qt) loadKV(t + 1, k0a, k0b, k0c, k0d, v0a, v0b, v0c, v0d);
    body(t == qt, k1a, k1b, k1c, k1d, v1a, v1b, v1c, v1d);
    if (++t > qt) break;
  }

  const float rl = 1.f / l_run;
  unsigned short* op = ctx + (size_t)(b*N_ + qt*32 + lq) * DOUT + h*HD_ + 4*hi;
  #pragma unroll
  for (int dt = 0; dt < 2; ++dt) {
    #pragma unroll
    for (int rq = 0; rq < 4; ++rq) {
      const float a0 = (dt ? acc1[4*rq+0] : acc0[4*rq+0]) * rl;
      const float a1 = (dt ? acc1[4*rq+1] : acc0[4*rq+1]) * rl;
      const float a2 = (dt ? acc1[4*rq+2] : acc0[4*rq+2]) * rl;
      const float a3 = (dt ? acc1[4*rq+3] : acc0[4*rq+3]) * rl;
      ushort4 st;
      st.x = f2bf(a0); st.y = f2bf(a1); st.z = f2bf(a2); st.w = f2bf(a3);
      *reinterpret_cast<ushort4*>(op + dt*32 + rq*8) = st;
    }
  }
}

// ---------------- launcher ----------------
extern "C" void kernel_launch(void* const* d_in, const int* in_sizes, int n_in,
                              void* d_out, int out_size, void* d_ws, size_t ws_size,
                              hipStream_t stream) {
  const float* x    = (const float*)d_in[0];
  const float* cosT = (const float*)d_in[1];
  const float* sinT = (const float*)d_in[2];
  const float* Wq   = (const float*)d_in[4];
  const float* Wk   = (const float*)d_in[5];
  const float* Wv   = (const float*)d_in[6];
  const float* Wo   = (const float*)d_in[7];
  float* out = (float*)d_out;

  char* ws = (char*)d_ws;
  unsigned short* xb    = (unsigned short*)(ws);               // 16 MB (reused as ctxb)
  unsigned short* ctxb  = xb;
  unsigned short* Wq_t  = (unsigned short*)(ws + 16777216);    // 8 MB; first 4 MB reused as Vt
  unsigned short* Vt    = Wq_t;
  unsigned short* Kp    = (unsigned short*)(ws + 20971520);    // 4 MB (2nd half of Wq_t region)
  unsigned short* Wkv_t = (unsigned short*)(ws + 25165824);    // 4 MB (reused as Vp)
  unsigned short* Vp    = Wkv_t;
  unsigned short* Wo_t  = (unsigned short*)(ws + 29360128);    // 8 MB
  unsigned short* Qb    = (unsigned short*)(ws + 37748736);    // 16 MB
  unsigned short* KVb   = (unsigned short*)(ws + 54525952);    // 8 MB

  k_cvt<<<dim3(M_*DIN/4/256), dim3(256), 0, stream>>>(x, xb, M_*DIN/4);

  dim3 tb(32, 8);
  k_transpose<<<dim3(DOUT/32, DIN/32), tb, 0, stream>>>(Wq, Wq_t, DIN, DOUT);
  k_transpose<<<dim3(512/32,  DIN/32), tb, 0, stream>>>(Wk, Wkv_t, DIN, 512);
  k_transpose<<<dim3(512/32,  DIN/32), tb, 0, stream>>>(Wv, Wkv_t + (size_t)512*DIN, DIN, 512);
  k_transpose<<<dim3(DOUT/32, DOUT/32), tb, 0, stream>>>(Wo, Wo_t, DOUT, DOUT);

  k_gemm_bt<unsigned short><<<dim3(DOUT/128, M_/128), 256, 0, stream>>>(xb, Wq_t,  Qb,  M_, DOUT, DIN);
  k_gemm_bt<unsigned short><<<dim3(1024/128, M_/128), 256, 0, stream>>>(xb, Wkv_t, KVb, M_, 1024, DIN);

  const float QSCALE = 0.125f * 1.44269504088896f;   // 1/sqrt(64) * log2(e)
  k_rope<<<dim3(M_*H_*32/256), dim3(256), 0, stream>>>(Qb,  cosT, sinT, H_, DOUT, QSCALE);
  k_rope<<<dim3(M_*G_*32/256), dim3(256), 0, stream>>>(KVb, cosT, sinT, G_, 1024, 1.0f);

  k_vtrans<<<dim3(64, 2, 16), tb, 0, stream>>>(KVb, Vt);
  k_pack<<<dim3(64, 16), dim3(64), 0, stream>>>(KVb, Vt, Kp, Vp);

  k_attn<<<dim3(1024), dim3(256), 0, stream>>>(Qb, Kp, Vp, ctxb);

  k_gemm_bt<float><<<dim3(DOUT/128, M_/128), 256, 0, stream>>>(ctxb, Wo_t, out, M_, DOUT, DIN);
}

// Round 7
// 261.993 us; speedup vs baseline: 1.2418x; 1.2418x over previous
//
#include <hip/hip_runtime.h>
#include <hip/hip_bf16.h>
#include <stdint.h>

#define B_   2
#define N_   2048
#define DIN  2048
#define DOUT 2048
#define H_   32
#define G_   8
#define HD_  64
#define M_   (B_*N_)   // 4096

using short8 = __attribute__((ext_vector_type(8))) short;
using f32x4  = __attribute__((ext_vector_type(4))) float;
using f32x16 = __attribute__((ext_vector_type(16))) float;
using int4v  = __attribute__((ext_vector_type(4))) int;

__device__ __forceinline__ unsigned short f2bf(float f) {
  unsigned int u = __float_as_uint(f);
  unsigned int r = u + 0x7FFFu + ((u >> 16) & 1u);
  return (unsigned short)(r >> 16);
}
__device__ __forceinline__ float bf2f(unsigned short h) {
  return __uint_as_float(((unsigned int)h) << 16);
}

// ---------------- elementwise f32 -> bf16 (4 elems/thread) ----------------
__global__ void k_cvt(const float* __restrict__ in, unsigned short* __restrict__ out, int n4) {
  int i = blockIdx.x * 256 + threadIdx.x;
  if (i >= n4) return;
  float4 v = reinterpret_cast<const float4*>(in)[i];
  uint2 o;
  o.x = (unsigned int)f2bf(v.x) | ((unsigned int)f2bf(v.y) << 16);
  o.y = (unsigned int)f2bf(v.z) | ((unsigned int)f2bf(v.w) << 16);
  reinterpret_cast<uint2*>(out)[i] = o;
}

// ---------------- transpose + convert: W (R x C) f32 -> Wt (C x R) bf16 ----------------
__global__ void k_transpose(const float* __restrict__ W, unsigned short* __restrict__ Wt,
                            int R, int C) {
  __shared__ float tile[32][33];
  int c0 = blockIdx.x * 32, r0 = blockIdx.y * 32;
  int tx = threadIdx.x, ty = threadIdx.y;  // (32,8)
  #pragma unroll
  for (int j = 0; j < 4; ++j)
    tile[ty + j*8][tx] = W[(size_t)(r0 + ty + j*8) * C + c0 + tx];
  __syncthreads();
  #pragma unroll
  for (int j = 0; j < 4; ++j)
    Wt[(size_t)(c0 + ty + j*8) * R + r0 + tx] = f2bf(tile[tx][ty + j*8]);
}

// ---------------- bf16 V-transpose: KVb V-half -> Vt[(b*8+g)*64 + d][n] ----------------
__global__ void k_vtrans(const unsigned short* __restrict__ KV, unsigned short* __restrict__ Vt) {
  __shared__ unsigned short tile[32][33];
  int nt = blockIdx.x;   // 0..63 (n tile)
  int dt = blockIdx.y;   // 0..1  (d tile)
  int bg = blockIdx.z;   // 0..15 (b*8+g)
  int b = bg >> 3, g = bg & 7;
  int tx = threadIdx.x, ty = threadIdx.y;  // (32,8)
  const unsigned short* src = KV + (size_t)(b*2048 + nt*32) * 1024 + 512 + g*64 + dt*32;
  #pragma unroll
  for (int j = 0; j < 4; ++j)
    tile[ty + j*8][tx] = src[(size_t)(ty + j*8) * 1024 + tx];   // [n_local][d_local]
  __syncthreads();
  unsigned short* dst = Vt + ((size_t)bg*64 + dt*32) * (size_t)N_ + nt*32;
  #pragma unroll
  for (int j = 0; j < 4; ++j)
    dst[(size_t)(ty + j*8) * N_ + tx] = tile[tx][ty + j*8];     // [d_local][n_local]
}

// ---------------- fragment-linear K/V tile pack ----------------
// Kp/Vp: per (bg, t) a 2048-element (4 KB) tile laid out EXACTLY in load order:
//   element index = chunk*512 + lane*8 + j.
__global__ void __launch_bounds__(64)
k_pack(const unsigned short* __restrict__ KV, const unsigned short* __restrict__ Vt,
       unsigned short* __restrict__ Kp, unsigned short* __restrict__ Vp) {
  const int t  = blockIdx.x;      // 0..63
  const int bg = blockIdx.y;      // 0..15
  const int b = bg >> 3, g = bg & 7;
  const int l = threadIdx.x;
  const int lo = l & 31, hi = l >> 5;
  const size_t base = ((size_t)bg*64 + t) * 2048;
  #pragma unroll
  for (int c = 0; c < 4; ++c) {
    short8 kv = *reinterpret_cast<const short8*>(
        KV + (size_t)(b*2048 + t*32 + lo) * 1024 + g*64 + c*16 + hi*8);
    *reinterpret_cast<short8*>(Kp + base + c*512 + l*8) = kv;
    short8 vv = *reinterpret_cast<const short8*>(
        Vt + ((size_t)bg*64 + (c>>1)*32 + lo) * (size_t)N_ + t*32 + (c&1)*16 + hi*8);
    *reinterpret_cast<short8*>(Vp + base + c*512 + l*8) = vv;
  }
}

// ---------------- in-place RoPE on bf16, optional output scale ----------------
__global__ void k_rope(unsigned short* __restrict__ X, const float* __restrict__ cosT,
                       const float* __restrict__ sinT, int nheads, int rowStride, float scale) {
  int idx = blockIdx.x * 256 + threadIdx.x;
  int dp  = idx & 31;
  int hh  = (idx >> 5) % nheads;
  int row = idx / (32 * nheads);
  if (row >= M_) return;
  int n = row & (N_ - 1);
  float c = cosT[n*HD_ + dp] * scale, s = sinT[n*HD_ + dp] * scale;
  unsigned short* p = X + (size_t)row * rowStride + hh*HD_ + dp;
  float x1 = bf2f(p[0]), x2 = bf2f(p[32]);
  p[0]  = f2bf(x1*c - x2*s);
  p[32] = f2bf(x2*c + x1*s);
}

// ---------------- bf16 GEMM, B given transposed (Bt: N x K row-major) ----------------
// T1: bijective XCD swizzle (m204) so each XCD's L2 serves a contiguous tile strip.
template <typename OUT>
__global__ void __launch_bounds__(256)
k_gemm_bt(const unsigned short* __restrict__ A, const unsigned short* __restrict__ Bt,
          OUT* __restrict__ C, int M, int N, int K) {
  __shared__ unsigned short As[128 * 32];
  __shared__ unsigned short Bs[128 * 32];
  const int tid  = threadIdx.x;
  const int wid  = tid >> 6, l = tid & 63;
  const int lrow = l & 15,  lk = l >> 4;
  const int wm = wid >> 1,  wn = wid & 1;

  // XCD-aware remap: hardware sends block n to XCD n%8; give each XCD a
  // contiguous range of tile ids.
  const int gx   = gridDim.x;
  const int nwg  = gx * gridDim.y;
  const int orig = blockIdx.y * gx + blockIdx.x;
  const int q8   = nwg >> 3, r8 = nwg & 7;
  const int xcd  = orig & 7, lin = orig >> 3;
  const int wg   = (xcd < r8 ? xcd*(q8+1) : r8*(q8+1) + (xcd - r8)*q8) + lin;
  const int bx   = wg % gx, by = wg / gx;

  const int rowA0 = by * 128, rowB0 = bx * 128;

  f32x4 acc[4][4];
  #pragma unroll
  for (int m = 0; m < 4; ++m)
    #pragma unroll
    for (int n = 0; n < 4; ++n)
      #pragma unroll
      for (int r = 0; r < 4; ++r) acc[m][n][r] = 0.f;

  int srow[2], scol[2];
  #pragma unroll
  for (int issue = 0; issue < 2; ++issue) {
    int slot = issue*4096 + wid*1024 + l*16;
    int row  = slot >> 6;
    int cp   = (slot >> 4) & 3;
    int sw   = (row & 3) ^ ((row >> 2) & 3);
    srow[issue] = row;
    scol[issue] = (cp ^ sw) * 8;
  }
  const int swr    = (lrow & 3) ^ ((lrow >> 2) & 3);
  const int rchunk = (lk ^ swr) * 8;

  for (int kt = 0; kt < K; kt += 32) {
    __syncthreads();
    #pragma unroll
    for (int issue = 0; issue < 2; ++issue) {
      const unsigned short* ga = A  + (size_t)(rowA0 + srow[issue]) * K + kt + scol[issue];
      const unsigned short* gb = Bt + (size_t)(rowB0 + srow[issue]) * K + kt + scol[issue];
      __builtin_amdgcn_global_load_lds(
          (const __attribute__((address_space(1))) unsigned int*)ga,
          (__attribute__((address_space(3))) unsigned int*)((char*)As + issue*4096 + wid*1024),
          16, 0, 0);
      __builtin_amdgcn_global_load_lds(
          (const __attribute__((address_space(1))) unsigned int*)gb,
          (__attribute__((address_space(3))) unsigned int*)((char*)Bs + issue*4096 + wid*1024),
          16, 0, 0);
    }
    asm volatile("s_waitcnt vmcnt(0)" ::: "memory");
    __syncthreads();

    short8 av[4], bv[4];
    #pragma unroll
    for (int m = 0; m < 4; ++m)
      av[m] = *reinterpret_cast<const short8*>(&As[(wm*64 + m*16 + lrow)*32 + rchunk]);
    #pragma unroll
    for (int n = 0; n < 4; ++n)
      bv[n] = *reinterpret_cast<const short8*>(&Bs[(wn*64 + n*16 + lrow)*32 + rchunk]);
    #pragma unroll
    for (int m = 0; m < 4; ++m)
      #pragma unroll
      for (int n = 0; n < 4; ++n)
        acc[m][n] = __builtin_amdgcn_mfma_f32_16x16x32_bf16(av[m], bv[n], acc[m][n], 0, 0, 0);
  }

  #pragma unroll
  for (int m = 0; m < 4; ++m) {
    int row0 = rowA0 + wm*64 + m*16 + lk*4;
    #pragma unroll
    for (int n = 0; n < 4; ++n) {
      int col = rowB0 + wn*64 + n*16 + lrow;
      #pragma unroll
      for (int r = 0; r < 4; ++r) {
        float v = acc[m][n][r];
        if constexpr (sizeof(OUT) == 2) C[(size_t)(row0 + r) * N + col] = (OUT)f2bf(v);
        else                            C[(size_t)(row0 + r) * N + col] = v;
      }
    }
  }
}

// ---------------- causal GQA flash attention v7 ----------------
// 4-wave blocks (4 heads of same (b,g,qt)); waves fully independent, no LDS/barriers.
// launch_bounds(256,2): 256-reg unified cap -> NO spills (r6's (256,4) cap=128 spilled).
// Fragment-linear Kp/Vp; longest-qt-first; ping-pong register prefetch;
// Q pre-scaled by 0.125*log2e; T13 defer-max; T12 permlane32_swap P-pack.
__global__ void __launch_bounds__(256, 2)
k_attn(const unsigned short* __restrict__ Q, const unsigned short* __restrict__ Kp,
       const unsigned short* __restrict__ Vp, unsigned short* __restrict__ ctx) {
  const int bid = blockIdx.x;            // 0..1023
  const int c   = bid & 15;              // (b,g) chunk -> fixed XCD
  const int b   = c >> 3, g = c & 7;
  const int qt  = 63 - (bid >> 4);       // longest first
  const int hh  = threadIdx.x >> 6;      // wave id = head within group
  const int h   = g*4 + hh;
  const int l   = threadIdx.x & 63;
  const int lq  = l & 31, hi = l >> 5;

  const unsigned short* qp = Q + (size_t)(b*N_ + qt*32 + lq) * DOUT + h*HD_ + hi*8;
  short8 qf0 = *reinterpret_cast<const short8*>(qp);
  short8 qf1 = *reinterpret_cast<const short8*>(qp + 16);
  short8 qf2 = *reinterpret_cast<const short8*>(qp + 32);
  short8 qf3 = *reinterpret_cast<const short8*>(qp + 48);

  const unsigned short* kpb = Kp + (size_t)c*64*2048 + l*8;
  const unsigned short* vpb = Vp + (size_t)c*64*2048 + l*8;

  f32x16 acc0, acc1;
  #pragma unroll
  for (int r = 0; r < 16; ++r) { acc0[r] = 0.f; acc1[r] = 0.f; }
  float m_run = -3.0e38f, l_run = 0.f;

  short8 k0a, k0b, k0c, k0d, v0a, v0b, v0c, v0d;   // ping
  short8 k1a, k1b, k1c, k1d, v1a, v1b, v1c, v1d;   // pong

  auto loadKV = [&](int t, short8& ka, short8& kb, short8& kc, short8& kd,
                            short8& va, short8& vb, short8& vc, short8& vd) {
    const unsigned short* kp = kpb + (size_t)t*2048;
    ka = *reinterpret_cast<const short8*>(kp);
    kb = *reinterpret_cast<const short8*>(kp + 512);
    kc = *reinterpret_cast<const short8*>(kp + 1024);
    kd = *reinterpret_cast<const short8*>(kp + 1536);
    const unsigned short* vp = vpb + (size_t)t*2048;
    va = *reinterpret_cast<const short8*>(vp);
    vb = *reinterpret_cast<const short8*>(vp + 512);
    vc = *reinterpret_cast<const short8*>(vp + 1024);
    vd = *reinterpret_cast<const short8*>(vp + 1536);
  };

  auto body = [&](bool diag, short8& ka, short8& kb, short8& kc, short8& kd,
                             short8& va, short8& vb, short8& vc, short8& vd) {
    f32x16 s;
    #pragma unroll
    for (int r = 0; r < 16; ++r) s[r] = 0.f;
    s = __builtin_amdgcn_mfma_f32_32x32x16_bf16(ka, qf0, s, 0, 0, 0);
    s = __builtin_amdgcn_mfma_f32_32x32x16_bf16(kb, qf1, s, 0, 0, 0);
    s = __builtin_amdgcn_mfma_f32_32x32x16_bf16(kc, qf2, s, 0, 0, 0);
    s = __builtin_amdgcn_mfma_f32_32x32x16_bf16(kd, qf3, s, 0, 0, 0);

    if (diag) {
      #pragma unroll
      for (int r = 0; r < 16; ++r) {
        const int ko = (r & 3) + 8*(r >> 2) + 4*hi;
        s[r] = (ko <= lq) ? s[r] : -3.0e38f;
      }
    }
    float t0 = fmaxf(fmaxf(s[0], s[1]), s[2]);
    float t1 = fmaxf(fmaxf(s[3], s[4]), s[5]);
    float t2 = fmaxf(fmaxf(s[6], s[7]), s[8]);
    float t3 = fmaxf(fmaxf(s[9], s[10]), s[11]);
    float t4 = fmaxf(fmaxf(s[12], s[13]), s[14]);
    float mt = fmaxf(fmaxf(fmaxf(t0, t1), fmaxf(t2, t3)), fmaxf(t4, s[15]));
    mt = fmaxf(mt, __shfl_xor(mt, 32));
    if (!__all(mt <= m_run + 8.f)) {          // T13 defer-max
      float nm = fmaxf(m_run, mt);
      float fr = exp2f(m_run - nm);
      m_run = nm;
      l_run *= fr;
      #pragma unroll
      for (int r = 0; r < 16; ++r) { acc0[r] *= fr; acc1[r] *= fr; }
    }
    unsigned int w[8];
    float ps = 0.f;
    #pragma unroll
    for (int i = 0; i < 8; ++i) {
      float p0 = exp2f(s[2*i]   - m_run);
      float p1 = exp2f(s[2*i+1] - m_run);
      ps += p0 + p1;
      asm("v_cvt_pk_bf16_f32 %0, %1, %2" : "=v"(w[i]) : "v"(p0), "v"(p1));
    }
    ps += __shfl_xor(ps, 32);
    l_run += ps;

    // T12: permlane32_swap builds both halves of each P fragment word
    unsigned int x0 = w[0], x1 = w[1], y0 = w[2], y1 = w[3];
    asm("v_permlane32_swap_b32 %0, %1" : "+v"(x0), "+v"(y0));
    asm("v_permlane32_swap_b32 %0, %1" : "+v"(x1), "+v"(y1));
    unsigned int x2 = w[4], x3 = w[5], y2 = w[6], y3 = w[7];
    asm("v_permlane32_swap_b32 %0, %1" : "+v"(x2), "+v"(y2));
    asm("v_permlane32_swap_b32 %0, %1" : "+v"(x3), "+v"(y3));
    int4v p0i, p1i;
    p0i[0] = (int)x0; p0i[1] = (int)x1; p0i[2] = (int)y0; p0i[3] = (int)y1;
    p1i[0] = (int)x2; p1i[1] = (int)x3; p1i[2] = (int)y2; p1i[3] = (int)y3;
    short8 pa0 = __builtin_bit_cast(short8, p0i);
    short8 pa1 = __builtin_bit_cast(short8, p1i);

    acc0 = __builtin_amdgcn_mfma_f32_32x32x16_bf16(va, pa0, acc0, 0, 0, 0);
    acc0 = __builtin_amdgcn_mfma_f32_32x32x16_bf16(vb, pa1, acc0, 0, 0, 0);
    acc1 = __builtin_amdgcn_mfma_f32_32x32x16_bf16(vc, pa0, acc1, 0, 0, 0);
    acc1 = __builtin_amdgcn_mfma_f32_32x32x16_bf16(vd, pa1, acc1, 0, 0, 0);
  };

  loadKV(0, k0a, k0b, k0c, k0d, v0a, v0b, v0c, v0d);
  int t = 0;
  while (true) {
    if (t + 1 <= qt) loadKV(t + 1, k1a, k1b, k1c, k1d, v1a, v1b, v1c, v1d);
    body(t == qt, k0a, k0b, k0c, k0d, v0a, v0b, v0c, v0d);
    if (++t > qt) break;
    if (t + 1 <= qt) loadKV(t + 1, k0a, k0b, k0c, k0d, v0a, v0b, v0c, v0d);
    body(t == qt, k1a, k1b, k1c, k1d, v1a, v1b, v1c, v1d);
    if (++t > qt) break;
  }

  const float rl = 1.f / l_run;
  unsigned short* op = ctx + (size_t)(b*N_ + qt*32 + lq) * DOUT + h*HD_ + 4*hi;
  #pragma unroll
  for (int dt = 0; dt < 2; ++dt) {
    #pragma unroll
    for (int rq = 0; rq < 4; ++rq) {
      const float a0 = (dt ? acc1[4*rq+0] : acc0[4*rq+0]) * rl;
      const float a1 = (dt ? acc1[4*rq+1] : acc0[4*rq+1]) * rl;
      const float a2 = (dt ? acc1[4*rq+2] : acc0[4*rq+2]) * rl;
      const float a3 = (dt ? acc1[4*rq+3] : acc0[4*rq+3]) * rl;
      ushort4 st;
      st.x = f2bf(a0); st.y = f2bf(a1); st.z = f2bf(a2); st.w = f2bf(a3);
      *reinterpret_cast<ushort4*>(op + dt*32 + rq*8) = st;
    }
  }
}

// ---------------- launcher ----------------
extern "C" void kernel_launch(void* const* d_in, const int* in_sizes, int n_in,
                              void* d_out, int out_size, void* d_ws, size_t ws_size,
                              hipStream_t stream) {
  const float* x    = (const float*)d_in[0];
  const float* cosT = (const float*)d_in[1];
  const float* sinT = (const float*)d_in[2];
  const float* Wq   = (const float*)d_in[4];
  const float* Wk   = (const float*)d_in[5];
  const float* Wv   = (const float*)d_in[6];
  const float* Wo   = (const float*)d_in[7];
  float* out = (float*)d_out;

  char* ws = (char*)d_ws;
  unsigned short* xb    = (unsigned short*)(ws);               // 16 MB (reused as ctxb)
  unsigned short* ctxb  = xb;
  unsigned short* Wq_t  = (unsigned short*)(ws + 16777216);    // 8 MB; first 4 MB reused as Vt
  unsigned short* Vt    = Wq_t;
  unsigned short* Kp    = (unsigned short*)(ws + 20971520);    // 4 MB (2nd half of Wq_t region)
  unsigned short* Wkv_t = (unsigned short*)(ws + 25165824);    // 4 MB (reused as Vp)
  unsigned short* Vp    = Wkv_t;
  unsigned short* Wo_t  = (unsigned short*)(ws + 29360128);    // 8 MB
  unsigned short* Qb    = (unsigned short*)(ws + 37748736);    // 16 MB
  unsigned short* KVb   = (unsigned short*)(ws + 54525952);    // 8 MB

  k_cvt<<<dim3(M_*DIN/4/256), dim3(256), 0, stream>>>(x, xb, M_*DIN/4);

  dim3 tb(32, 8);
  k_transpose<<<dim3(DOUT/32, DIN/32), tb, 0, stream>>>(Wq, Wq_t, DIN, DOUT);
  k_transpose<<<dim3(512/32,  DIN/32), tb, 0, stream>>>(Wk, Wkv_t, DIN, 512);
  k_transpose<<<dim3(512/32,  DIN/32), tb, 0, stream>>>(Wv, Wkv_t + (size_t)512*DIN, DIN, 512);
  k_transpose<<<dim3(DOUT/32, DOUT/32), tb, 0, stream>>>(Wo, Wo_t, DOUT, DOUT);

  k_gemm_bt<unsigned short><<<dim3(DOUT/128, M_/128), 256, 0, stream>>>(xb, Wq_t,  Qb,  M_, DOUT, DIN);
  k_gemm_bt<unsigned short><<<dim3(1024/128, M_/128), 256, 0, stream>>>(xb, Wkv_t, KVb, M_, 1024, DIN);

  const float QSCALE = 0.125f * 1.44269504088896f;   // 1/sqrt(64) * log2(e)
  k_rope<<<dim3(M_*H_*32/256), dim3(256), 0, stream>>>(Qb,  cosT, sinT, H_, DOUT, QSCALE);
  k_rope<<<dim3(M_*G_*32/256), dim3(256), 0, stream>>>(KVb, cosT, sinT, G_, 1024, 1.0f);

  k_vtrans<<<dim3(64, 2, 16), tb, 0, stream>>>(KVb, Vt);
  k_pack<<<dim3(64, 16), dim3(64), 0, stream>>>(KVb, Vt, Kp, Vp);

  k_attn<<<dim3(1024), dim3(256), 0, stream>>>(Qb, Kp, Vp, ctxb);

  k_gemm_bt<float><<<dim3(DOUT/128, M_/128), 256, 0, stream>>>(ctxb, Wo_t, out, M_, DOUT, DIN);
}